// Round 6
// baseline (73.520 us; speedup 1.0000x reference)
//
#include <hip/hip_runtime.h>

// LCALayer: per-row (N=2e6, D=8) elementwise update.
// recur = sum(activities @ gamma) = -0.7 * rowsum(activities)
// active = all(|activities| < 1) ? 1 : 0
// pre = pa + (inp - 0.1*pa + recur) * active * 0.01 + nr * active * sqrt(0.001)
// act = relu(pre)
//
// R5 post-mortem: 2 rows/thread + NT stores = 67.0 us (93% of copy ceiling).
// R6: 4 rows/thread (32 outstanding 16B loads/thread ~ vmcnt window), pure
// ILP latency hiding. NT stores kept (R4 A/B: cached stores cost +5 us via
// L2 write-allocate pollution despite lower HBM write bytes).

#define THRESHOLD 1.0f
#define LEAK 0.1f
#define TSTEP 0.01f
#define SQRT_STEP 0.031622776601683794f  // sqrt(0.001)

typedef float vfloat4 __attribute__((ext_vector_type(4)));

#define ROWS_PER_THREAD 4

__global__ __launch_bounds__(256) void lca_kernel(
    const float* __restrict__ inp,
    const float* __restrict__ pa,
    const float* __restrict__ acts,
    const float* __restrict__ nr,
    float* __restrict__ out_pre,
    float* __restrict__ out_act,
    float* __restrict__ out_active,
    int n)
{
    // block handles 1024 consecutive rows in 4 wave-contiguous strips
    const int r0 = blockIdx.x * (256 * ROWS_PER_THREAD) + threadIdx.x;

    int   row[ROWS_PER_THREAD];
    bool  ok[ROWS_PER_THREAD];
    size_t b[ROWS_PER_THREAD];
#pragma unroll
    for (int k = 0; k < ROWS_PER_THREAD; ++k) {
        row[k] = r0 + k * 256;
        ok[k]  = row[k] < n;
        b[k]   = (size_t)row[k] * 8;
    }

    // issue ALL loads up front (up to 32 outstanding 16B loads per thread)
    vfloat4 va0[ROWS_PER_THREAD], va1[ROWS_PER_THREAD];
    vfloat4 vi0[ROWS_PER_THREAD], vi1[ROWS_PER_THREAD];
    vfloat4 vp0[ROWS_PER_THREAD], vp1[ROWS_PER_THREAD];
    vfloat4 vn0[ROWS_PER_THREAD], vn1[ROWS_PER_THREAD];

#pragma unroll
    for (int k = 0; k < ROWS_PER_THREAD; ++k) {
        if (ok[k]) {
            va0[k] = *reinterpret_cast<const vfloat4*>(acts + b[k]);
            va1[k] = *reinterpret_cast<const vfloat4*>(acts + b[k] + 4);
            vi0[k] = *reinterpret_cast<const vfloat4*>(inp + b[k]);
            vi1[k] = *reinterpret_cast<const vfloat4*>(inp + b[k] + 4);
            vp0[k] = *reinterpret_cast<const vfloat4*>(pa + b[k]);
            vp1[k] = *reinterpret_cast<const vfloat4*>(pa + b[k] + 4);
            vn0[k] = *reinterpret_cast<const vfloat4*>(nr + b[k]);
            vn1[k] = *reinterpret_cast<const vfloat4*>(nr + b[k] + 4);
        }
    }

#pragma unroll
    for (int k = 0; k < ROWS_PER_THREAD; ++k) {
        if (!ok[k]) continue;

        float a[8] = {va0[k].x, va0[k].y, va0[k].z, va0[k].w,
                      va1[k].x, va1[k].y, va1[k].z, va1[k].w};
        bool all_below = true;
        float S = 0.0f;
#pragma unroll
        for (int j = 0; j < 8; ++j) {
            all_below = all_below && (fabsf(a[j]) < THRESHOLD);
            S += a[j];
        }
        const float active = all_below ? 1.0f : 0.0f;
        const float recur = -0.7f * S;

        float iv[8] = {vi0[k].x, vi0[k].y, vi0[k].z, vi0[k].w,
                       vi1[k].x, vi1[k].y, vi1[k].z, vi1[k].w};
        float pv[8] = {vp0[k].x, vp0[k].y, vp0[k].z, vp0[k].w,
                       vp1[k].x, vp1[k].y, vp1[k].z, vp1[k].w};
        float nv[8] = {vn0[k].x, vn0[k].y, vn0[k].z, vn0[k].w,
                       vn1[k].x, vn1[k].y, vn1[k].z, vn1[k].w};

        const float ts_a = active * TSTEP;
        const float ns_a = active * SQRT_STEP;

        float pr[8], ac[8];
#pragma unroll
        for (int j = 0; j < 8; ++j) {
            float x = iv[j] - LEAK * pv[j] + recur;
            float p = pv[j] + x * ts_a + nv[j] * ns_a;
            pr[j] = p;
            ac[j] = fmaxf(p, 0.0f);
        }

        vfloat4 pr0 = {pr[0], pr[1], pr[2], pr[3]};
        vfloat4 pr1 = {pr[4], pr[5], pr[6], pr[7]};
        vfloat4 ac0 = {ac[0], ac[1], ac[2], ac[3]};
        vfloat4 ac1 = {ac[4], ac[5], ac[6], ac[7]};

        __builtin_nontemporal_store(pr0, reinterpret_cast<vfloat4*>(out_pre + b[k]));
        __builtin_nontemporal_store(pr1, reinterpret_cast<vfloat4*>(out_pre + b[k] + 4));
        __builtin_nontemporal_store(ac0, reinterpret_cast<vfloat4*>(out_act + b[k]));
        __builtin_nontemporal_store(ac1, reinterpret_cast<vfloat4*>(out_act + b[k] + 4));
        __builtin_nontemporal_store(active, out_active + row[k]);
    }
}

extern "C" void kernel_launch(void* const* d_in, const int* in_sizes, int n_in,
                              void* d_out, int out_size, void* d_ws, size_t ws_size,
                              hipStream_t stream) {
    const float* inp  = (const float*)d_in[0];
    const float* pa   = (const float*)d_in[1];
    const float* acts = (const float*)d_in[2];
    const float* nr   = (const float*)d_in[3];

    const int n = in_sizes[0] / 8;  // 2,000,000 rows

    float* out = (float*)d_out;
    float* out_pre    = out;                    // [n, 8]
    float* out_act    = out + (size_t)n * 8;    // [n, 8]
    float* out_active = out + (size_t)n * 16;   // [n, 1]

    const int block = 256;
    const int rows_per_block = block * ROWS_PER_THREAD;  // 1024
    const int grid = (n + rows_per_block - 1) / rows_per_block;
    lca_kernel<<<grid, block, 0, stream>>>(inp, pa, acts, nr,
                                           out_pre, out_act, out_active, n);
}

// Round 7
// 60.786 us; speedup vs baseline: 1.2095x; 1.2095x over previous
//
#include <hip/hip_runtime.h>

// LCALayer: per-row (N=2e6, D=8) elementwise update.
// recur = sum(activities @ gamma) = -0.7 * rowsum(activities)
// active = all(|activities| < 1) ? 1 : 0
// pre = pa + (inp - 0.1*pa + recur) * active * 0.01 + nr * active * sqrt(0.001)
// act = relu(pre)
//
// R6 post-mortem: 4 rows/thread -> VGPR 88, occupancy 19%, 73.5 us. Reverted
// to 2 rows/thread (R5 = 67.0 us sweet spot).
// R7: LDS-repacked output stores. Row-per-lane NT stores write 16B at 32B
// stride per instruction (half-sector HBM writes, WRITE_SIZE 147 vs 136 MB
// ideal). Stage pre/act through per-wave LDS so each NT store instruction
// covers a dense 1KB wave-contiguous span. LDS was idle; VALUBusy 3%.

#define THRESHOLD 1.0f
#define LEAK 0.1f
#define TSTEP 0.01f
#define SQRT_STEP 0.031622776601683794f  // sqrt(0.001)

typedef float vfloat4 __attribute__((ext_vector_type(4)));

__device__ __forceinline__ void lca_math(
    const vfloat4& va0, const vfloat4& va1,
    const vfloat4& vi0, const vfloat4& vi1,
    const vfloat4& vp0, const vfloat4& vp1,
    const vfloat4& vn0, const vfloat4& vn1,
    vfloat4& pr0, vfloat4& pr1, vfloat4& ac0, vfloat4& ac1,
    float& active_out)
{
    float a[8] = {va0.x, va0.y, va0.z, va0.w, va1.x, va1.y, va1.z, va1.w};
    bool all_below = true;
    float S = 0.0f;
#pragma unroll
    for (int j = 0; j < 8; ++j) {
        all_below = all_below && (fabsf(a[j]) < THRESHOLD);
        S += a[j];
    }
    const float active = all_below ? 1.0f : 0.0f;
    const float recur = -0.7f * S;

    float iv[8] = {vi0.x, vi0.y, vi0.z, vi0.w, vi1.x, vi1.y, vi1.z, vi1.w};
    float pv[8] = {vp0.x, vp0.y, vp0.z, vp0.w, vp1.x, vp1.y, vp1.z, vp1.w};
    float nv[8] = {vn0.x, vn0.y, vn0.z, vn0.w, vn1.x, vn1.y, vn1.z, vn1.w};

    const float ts_a = active * TSTEP;
    const float ns_a = active * SQRT_STEP;

    float pr[8], ac[8];
#pragma unroll
    for (int j = 0; j < 8; ++j) {
        float x = iv[j] - LEAK * pv[j] + recur;
        float p = pv[j] + x * ts_a + nv[j] * ns_a;
        pr[j] = p;
        ac[j] = fmaxf(p, 0.0f);
    }
    pr0 = (vfloat4){pr[0], pr[1], pr[2], pr[3]};
    pr1 = (vfloat4){pr[4], pr[5], pr[6], pr[7]};
    ac0 = (vfloat4){ac[0], ac[1], ac[2], ac[3]};
    ac1 = (vfloat4){ac[4], ac[5], ac[6], ac[7]};
    active_out = active;
}

__global__ __launch_bounds__(256) void lca_kernel(
    const float* __restrict__ inp,
    const float* __restrict__ pa,
    const float* __restrict__ acts,
    const float* __restrict__ nr,
    float* __restrict__ out_pre,
    float* __restrict__ out_act,
    float* __restrict__ out_active,
    int n)
{
    // per-wave staging buffers: 4 waves x 64 rows x 8 floats (2KB each tensor)
    __shared__ __align__(16) float lds_pre[4][512];
    __shared__ __align__(16) float lds_act[4][512];

    const int tid  = threadIdx.x;
    const int wid  = tid >> 6;
    const int lane = tid & 63;
    const int blockBase = blockIdx.x * 512;  // block covers 512 consecutive rows

    const int rA = blockBase + tid;          // strip A
    const int rB = rA + 256;                 // strip B
    const size_t bA = (size_t)rA * 8;
    const size_t bB = (size_t)rB * 8;

    const bool full = (blockBase + 512) <= n;

    if (full) {
        // ---- all 16 loads up front (ILP) ----
        vfloat4 Aa0 = *reinterpret_cast<const vfloat4*>(acts + bA);
        vfloat4 Aa1 = *reinterpret_cast<const vfloat4*>(acts + bA + 4);
        vfloat4 Ai0 = *reinterpret_cast<const vfloat4*>(inp + bA);
        vfloat4 Ai1 = *reinterpret_cast<const vfloat4*>(inp + bA + 4);
        vfloat4 Ap0 = *reinterpret_cast<const vfloat4*>(pa + bA);
        vfloat4 Ap1 = *reinterpret_cast<const vfloat4*>(pa + bA + 4);
        vfloat4 An0 = *reinterpret_cast<const vfloat4*>(nr + bA);
        vfloat4 An1 = *reinterpret_cast<const vfloat4*>(nr + bA + 4);
        vfloat4 Ba0 = *reinterpret_cast<const vfloat4*>(acts + bB);
        vfloat4 Ba1 = *reinterpret_cast<const vfloat4*>(acts + bB + 4);
        vfloat4 Bi0 = *reinterpret_cast<const vfloat4*>(inp + bB);
        vfloat4 Bi1 = *reinterpret_cast<const vfloat4*>(inp + bB + 4);
        vfloat4 Bp0 = *reinterpret_cast<const vfloat4*>(pa + bB);
        vfloat4 Bp1 = *reinterpret_cast<const vfloat4*>(pa + bB + 4);
        vfloat4 Bn0 = *reinterpret_cast<const vfloat4*>(nr + bB);
        vfloat4 Bn1 = *reinterpret_cast<const vfloat4*>(nr + bB + 4);

        // ---- strip A ----
        {
            vfloat4 pr0, pr1, ac0, ac1; float act;
            lca_math(Aa0, Aa1, Ai0, Ai1, Ap0, Ap1, An0, An1, pr0, pr1, ac0, ac1, act);
            // stage row-per-lane into wave-private LDS
            *reinterpret_cast<vfloat4*>(&lds_pre[wid][lane * 8])     = pr0;
            *reinterpret_cast<vfloat4*>(&lds_pre[wid][lane * 8 + 4]) = pr1;
            *reinterpret_cast<vfloat4*>(&lds_act[wid][lane * 8])     = ac0;
            *reinterpret_cast<vfloat4*>(&lds_act[wid][lane * 8 + 4]) = ac1;
            // read back linearly (wave-private, in-order ds ops: no barrier)
            vfloat4 q0 = *reinterpret_cast<const vfloat4*>(&lds_pre[wid][lane * 4]);
            vfloat4 q1 = *reinterpret_cast<const vfloat4*>(&lds_pre[wid][256 + lane * 4]);
            vfloat4 s0 = *reinterpret_cast<const vfloat4*>(&lds_act[wid][lane * 4]);
            vfloat4 s1 = *reinterpret_cast<const vfloat4*>(&lds_act[wid][256 + lane * 4]);
            // dense 1KB-per-instruction NT stores
            float* pdst = out_pre + (size_t)(blockBase + wid * 64) * 8;
            float* adst = out_act + (size_t)(blockBase + wid * 64) * 8;
            __builtin_nontemporal_store(q0, reinterpret_cast<vfloat4*>(pdst + lane * 4));
            __builtin_nontemporal_store(q1, reinterpret_cast<vfloat4*>(pdst + 256 + lane * 4));
            __builtin_nontemporal_store(s0, reinterpret_cast<vfloat4*>(adst + lane * 4));
            __builtin_nontemporal_store(s1, reinterpret_cast<vfloat4*>(adst + 256 + lane * 4));
            __builtin_nontemporal_store(act, out_active + rA);
        }
        // ---- strip B (reuses LDS; same-wave in-order ds ops make WAR safe) ----
        {
            vfloat4 pr0, pr1, ac0, ac1; float act;
            lca_math(Ba0, Ba1, Bi0, Bi1, Bp0, Bp1, Bn0, Bn1, pr0, pr1, ac0, ac1, act);
            *reinterpret_cast<vfloat4*>(&lds_pre[wid][lane * 8])     = pr0;
            *reinterpret_cast<vfloat4*>(&lds_pre[wid][lane * 8 + 4]) = pr1;
            *reinterpret_cast<vfloat4*>(&lds_act[wid][lane * 8])     = ac0;
            *reinterpret_cast<vfloat4*>(&lds_act[wid][lane * 8 + 4]) = ac1;
            vfloat4 q0 = *reinterpret_cast<const vfloat4*>(&lds_pre[wid][lane * 4]);
            vfloat4 q1 = *reinterpret_cast<const vfloat4*>(&lds_pre[wid][256 + lane * 4]);
            vfloat4 s0 = *reinterpret_cast<const vfloat4*>(&lds_act[wid][lane * 4]);
            vfloat4 s1 = *reinterpret_cast<const vfloat4*>(&lds_act[wid][256 + lane * 4]);
            float* pdst = out_pre + (size_t)(blockBase + 256 + wid * 64) * 8;
            float* adst = out_act + (size_t)(blockBase + 256 + wid * 64) * 8;
            __builtin_nontemporal_store(q0, reinterpret_cast<vfloat4*>(pdst + lane * 4));
            __builtin_nontemporal_store(q1, reinterpret_cast<vfloat4*>(pdst + 256 + lane * 4));
            __builtin_nontemporal_store(s0, reinterpret_cast<vfloat4*>(adst + lane * 4));
            __builtin_nontemporal_store(s1, reinterpret_cast<vfloat4*>(adst + 256 + lane * 4));
            __builtin_nontemporal_store(act, out_active + rB);
        }
    } else {
        // ---- tail block (at most one): R5-style guarded per-row path ----
        for (int s = 0; s < 2; ++s) {
            const int r = rA + s * 256;
            if (r >= n) continue;
            const size_t b = (size_t)r * 8;
            vfloat4 a0 = *reinterpret_cast<const vfloat4*>(acts + b);
            vfloat4 a1 = *reinterpret_cast<const vfloat4*>(acts + b + 4);
            vfloat4 i0 = *reinterpret_cast<const vfloat4*>(inp + b);
            vfloat4 i1 = *reinterpret_cast<const vfloat4*>(inp + b + 4);
            vfloat4 p0 = *reinterpret_cast<const vfloat4*>(pa + b);
            vfloat4 p1 = *reinterpret_cast<const vfloat4*>(pa + b + 4);
            vfloat4 n0 = *reinterpret_cast<const vfloat4*>(nr + b);
            vfloat4 n1 = *reinterpret_cast<const vfloat4*>(nr + b + 4);
            vfloat4 pr0, pr1, ac0, ac1; float act;
            lca_math(a0, a1, i0, i1, p0, p1, n0, n1, pr0, pr1, ac0, ac1, act);
            __builtin_nontemporal_store(pr0, reinterpret_cast<vfloat4*>(out_pre + b));
            __builtin_nontemporal_store(pr1, reinterpret_cast<vfloat4*>(out_pre + b + 4));
            __builtin_nontemporal_store(ac0, reinterpret_cast<vfloat4*>(out_act + b));
            __builtin_nontemporal_store(ac1, reinterpret_cast<vfloat4*>(out_act + b + 4));
            __builtin_nontemporal_store(act, out_active + r);
        }
    }
}

extern "C" void kernel_launch(void* const* d_in, const int* in_sizes, int n_in,
                              void* d_out, int out_size, void* d_ws, size_t ws_size,
                              hipStream_t stream) {
    const float* inp  = (const float*)d_in[0];
    const float* pa   = (const float*)d_in[1];
    const float* acts = (const float*)d_in[2];
    const float* nr   = (const float*)d_in[3];

    const int n = in_sizes[0] / 8;  // 2,000,000 rows

    float* out = (float*)d_out;
    float* out_pre    = out;                    // [n, 8]
    float* out_act    = out + (size_t)n * 8;    // [n, 8]
    float* out_active = out + (size_t)n * 16;   // [n, 1]

    const int block = 256;
    const int grid = (n + 511) / 512;           // 2 rows per thread
    lca_kernel<<<grid, block, 0, stream>>>(inp, pa, acts, nr,
                                           out_pre, out_act, out_active, n);
}